// Round 5
// baseline (6710.818 us; speedup 1.0000x reference)
//
#include <hip/hip_runtime.h>
#include <hip/hip_bf16.h>
#include <stdint.h>

// WiredRNN: h_{t+1} = tanh([h_t | x_t] @ [Wr;Wi] + b), B=32, L=8192, C=128, U=256, OUT=64.
// R5: MFMA dataflow. Transposed product C[n][b] = W^T(n,k) @ h^T(k,b) so that the
// lane-fixed index is b on both B-frag reads (h[b][k], contiguous b128) and C writes
// (packed b64 along reg-consecutive n). XW = x@Wi+b precomputed by an MFMA GEMM that
// stores directly in the scan's C-fragment order (coalesced dwordx4 both sides).
// Layouts (gfx950, verified in guide): C: col=lane&15, row=(lane>>4)*4+reg;
// A: m=lane&15, k=(lane>>4)*8+j; B: n=lane&15, k=(lane>>4)*8+j.

#define NB 32
#define SL 8192
#define NC 128
#define NU 256
#define NO 64
#define HSTR 264   // h_lds row stride (h16): 528 B; %16==0; 132 dw %32==4 -> phase-conflict-free
#define XSTR 136   // xs row stride (h16): 272 B; %16==0; 68 dw %32==4

typedef _Float16 h16;
typedef __attribute__((ext_vector_type(4))) _Float16 f16x4;
typedef __attribute__((ext_vector_type(8))) _Float16 f16x8;
typedef __attribute__((ext_vector_type(4))) float f32x4;

__device__ __forceinline__ float ftanh(float x) {
#if __has_builtin(__builtin_amdgcn_exp2f) && __has_builtin(__builtin_amdgcn_rcpf)
    float e = __builtin_amdgcn_exp2f(x * 2.8853900817779268f);   // e^{2x}
    return 1.0f - 2.0f * __builtin_amdgcn_rcpf(e + 1.0f);
#else
    return tanhf(x);
#endif
}

// ---------------- XW GEMM (MFMA): xw[t][wg][tid][e] = frag-ordered x@Wi_masked + bias ----
// grid (SL/32, 2); block 256. Wave w covers n-tiles 4w..4w+3; K=C=128 (4 k-steps of 32).
__global__ __launch_bounds__(256, 2) void xw_gemm_mfma(
    const float* __restrict__ x,     // [NB, SL, NC]
    const float* __restrict__ Wi,    // [NC, NU]
    const float* __restrict__ bias,  // [NU]
    const float* __restrict__ Mi,    // [NC, NU]
    h16* __restrict__ xw)            // [SL][2][256][16]
{
    const int tid  = threadIdx.x;
    const int wave = tid >> 6, lane = tid & 63;
    const int col  = lane & 15, quad = lane >> 4;
    const int wg   = blockIdx.y;           // batch half
    const int t0   = blockIdx.x * 32;

    __shared__ h16 xs[2][16 * XSTR];       // x^T tile staged as [b][c] f16, double-buffered

    // A-frags: Wi^T masked. A[m=n-in-tile][k=c]
    f16x8 afr[4][4];
#pragma unroll
    for (int ta = 0; ta < 4; ++ta) {
        const int n = (wave * 4 + ta) * 16 + col;
#pragma unroll
        for (int ks = 0; ks < 4; ++ks)
#pragma unroll
            for (int j = 0; j < 8; ++j) {
                const int c = ks * 32 + quad * 8 + j;
                afr[ta][ks][j] = (h16)(Wi[c * NU + n] * Mi[c * NU + n]);
            }
    }
    float binit[4][4];
#pragma unroll
    for (int ta = 0; ta < 4; ++ta)
#pragma unroll
        for (int r = 0; r < 4; ++r)
            binit[ta][r] = bias[(wave * 4 + ta) * 16 + quad * 4 + r];

    const int srow = tid >> 4;             // staging: b-in-half
    const int scol = (tid & 15) * 8;       // c start (8 fp32 per lane)

    // stage t0 into buf 0
    {
        const float4* xp = (const float4*)&x[(((long)(wg * 16 + srow)) * SL + t0) * NC + scol];
        float4 a = xp[0], b4 = xp[1];
        f16x8 v;
        v[0]=(h16)a.x;  v[1]=(h16)a.y;  v[2]=(h16)a.z;  v[3]=(h16)a.w;
        v[4]=(h16)b4.x; v[5]=(h16)b4.y; v[6]=(h16)b4.z; v[7]=(h16)b4.w;
        *(f16x8*)&xs[0][srow * XSTR + scol] = v;
    }
    __syncthreads();

    int buf = 0;
    for (int i = 0; i < 32; ++i) {
        const int t = t0 + i;
        if (i + 1 < 32) {   // stage next t into other buffer
            const float4* xp = (const float4*)&x[(((long)(wg * 16 + srow)) * SL + (t + 1)) * NC + scol];
            float4 a = xp[0], b4 = xp[1];
            f16x8 v;
            v[0]=(h16)a.x;  v[1]=(h16)a.y;  v[2]=(h16)a.z;  v[3]=(h16)a.w;
            v[4]=(h16)b4.x; v[5]=(h16)b4.y; v[6]=(h16)b4.z; v[7]=(h16)b4.w;
            *(f16x8*)&xs[buf ^ 1][srow * XSTR + scol] = v;
        }
        // B-frags: x^T[c][b] read from xs[b][c]
        f16x8 bfr[4];
#pragma unroll
        for (int ks = 0; ks < 4; ++ks)
            bfr[ks] = *(const f16x8*)&xs[buf][col * XSTR + ks * 32 + quad * 8];

        f32x4 acc[4];
#pragma unroll
        for (int ta = 0; ta < 4; ++ta)
#pragma unroll
            for (int r = 0; r < 4; ++r) acc[ta][r] = binit[ta][r];
#pragma unroll
        for (int ks = 0; ks < 4; ++ks)
#pragma unroll
            for (int ta = 0; ta < 4; ++ta)
                acc[ta] = __builtin_amdgcn_mfma_f32_16x16x32_f16(afr[ta][ks], bfr[ks], acc[ta], 0, 0, 0);

        // store frag-ordered (e = ta*4 + r)
        f16x8 o0, o1;
#pragma unroll
        for (int e = 0; e < 8; ++e)  o0[e] = (h16)acc[e >> 2][e & 3];
#pragma unroll
        for (int e = 8; e < 16; ++e) o1[e - 8] = (h16)acc[e >> 2][e & 3];
        f16x8* op = (f16x8*)&xw[(((long)t * 2 + wg) * 256 + tid) * 16];
        op[0] = o0; op[1] = o1;

        __syncthreads();
        buf ^= 1;
    }
}

// ---------------- recurrent scan (MFMA): 2 WGs x 256 thr, 16 batches each ----------------
__global__ __launch_bounds__(256, 1) void rnn_scan_mfma(
    const float* __restrict__ Wr,    // [NU, NU]
    const float* __restrict__ Mr,    // [NU, NU]
    const h16* __restrict__ xw,      // [SL][2][256][16] frag-ordered
    float* __restrict__ out)         // [NB*SL*NO] ++ [NB*NU]
{
    const int tid  = threadIdx.x;
    const int wave = tid >> 6, lane = tid & 63;
    const int col  = lane & 15, quad = lane >> 4;
    const int wg   = blockIdx.x;           // batch half

    __shared__ h16 hlds[16 * HSTR];        // h[b][k] f16

    // A-frags: Wr^T masked. K=256 -> 8 k-steps
    f16x8 afr[4][8];
#pragma unroll
    for (int ta = 0; ta < 4; ++ta) {
        const int n = (wave * 4 + ta) * 16 + col;
#pragma unroll
        for (int ks = 0; ks < 8; ++ks)
#pragma unroll
            for (int j = 0; j < 8; ++j) {
                const int k = ks * 32 + quad * 8 + j;
                afr[ta][ks][j] = (h16)(Wr[k * NU + n] * Mr[k * NU + n]);
            }
    }

    for (int i = tid; i < 16 * HSTR; i += 256) hlds[i] = (h16)0.f;

    f16x8 xc0, xc1;   // XW frags for current step (preload t=0)
    {
        const f16x8* p = (const f16x8*)&xw[((long)wg * 256 + tid) * 16];
        xc0 = p[0]; xc1 = p[1];
    }
    __syncthreads();

    const long out_h = (long)NB * SL * NO;

    for (int t = 0; t < SL; ++t) {
        // prefetch next step's XW
        f16x8 xn0 = xc0, xn1 = xc1;
        if (t + 1 < SL) {
            const f16x8* p = (const f16x8*)&xw[(((long)(t + 1) * 2 + wg) * 256 + tid) * 16];
            xn0 = p[0]; xn1 = p[1];
        }
        // B-frags: h^T[k][b] read from hlds[b][k] (contiguous b128 per k-step)
        f16x8 bfr[8];
#pragma unroll
        for (int ks = 0; ks < 8; ++ks)
            bfr[ks] = *(const f16x8*)&hlds[col * HSTR + ks * 32 + quad * 8];

        // acc init from XW (e = ta*4 + r)
        f32x4 acc[4];
#pragma unroll
        for (int ta = 0; ta < 4; ++ta)
#pragma unroll
            for (int r = 0; r < 4; ++r) {
                const int e = ta * 4 + r;
                acc[ta][r] = (e < 8) ? (float)xc0[e] : (float)xc1[e - 8];
            }
#pragma unroll
        for (int ks = 0; ks < 8; ++ks)
#pragma unroll
            for (int ta = 0; ta < 4; ++ta)
                acc[ta] = __builtin_amdgcn_mfma_f32_16x16x32_f16(afr[ta][ks], bfr[ks], acc[ta], 0, 0, 0);

        float hv[4][4];
#pragma unroll
        for (int ta = 0; ta < 4; ++ta)
#pragma unroll
            for (int r = 0; r < 4; ++r) hv[ta][r] = ftanh(acc[ta][r]);

        __syncthreads();   // all waves' B-frag reads complete before h overwrite

        // write h_new: C[n][b] -> hlds[b][n], reg-consecutive n packs to b64
#pragma unroll
        for (int ta = 0; ta < 4; ++ta) {
            const int n0 = (wave * 4 + ta) * 16 + quad * 4;
            f16x4 hp;
            hp[0]=(h16)hv[ta][0]; hp[1]=(h16)hv[ta][1]; hp[2]=(h16)hv[ta][2]; hp[3]=(h16)hv[ta][3];
            *(f16x4*)&hlds[col * HSTR + n0] = hp;
        }
        // readout: motor units n in [192,256) live entirely in wave 3
        if (wave == 3) {
            float* ob = &out[(((long)(wg * 16 + col)) * SL + t) * NO];
#pragma unroll
            for (int ta = 0; ta < 4; ++ta) {
                const int n0 = (12 + ta) * 16 + quad * 4;
                float4 v4 = make_float4(hv[ta][0], hv[ta][1], hv[ta][2], hv[ta][3]);
                *(float4*)&ob[n0 - 192] = v4;
            }
        }
        if (t == SL - 1) {   // h_last
            float* hb = &out[out_h + ((long)(wg * 16 + col)) * NU];
#pragma unroll
            for (int ta = 0; ta < 4; ++ta) {
                const int n0 = (wave * 4 + ta) * 16 + quad * 4;
                float4 v4 = make_float4(hv[ta][0], hv[ta][1], hv[ta][2], hv[ta][3]);
                *(float4*)&hb[n0] = v4;
            }
        }
        xc0 = xn0; xc1 = xn1;
        __syncthreads();
    }
}

// ---------------- fallback (R3-proven): direct K=384 fdot2 scan ----------------
typedef __attribute__((ext_vector_type(2))) _Float16 h16x2;
__device__ __forceinline__ float fdot2f(h16x2 a, h16x2 b, float c) {
#if __has_builtin(__builtin_amdgcn_fdot2)
    return __builtin_amdgcn_fdot2(a, b, c, false);
#else
    return c + (float)a[0] * (float)b[0] + (float)a[1] * (float)b[1];
#endif
}
__global__ __launch_bounds__(1024, 4) void rnn_scan_fallback(
    const float* __restrict__ x, const float* __restrict__ W_in,
    const float* __restrict__ W_rec, const float* __restrict__ bias,
    const float* __restrict__ M_in, const float* __restrict__ M_rec,
    float* __restrict__ out)
{
    const int tid = threadIdx.x, b = blockIdx.x;
    const int u = tid & (NU - 1), kc = tid >> 8, ks = kc * 96;
    __shared__ __align__(16) h16 vec[384];
    __shared__ float partial[4][NU];
    h16x2 w[48];
#pragma unroll
    for (int j = 0; j < 48; ++j) {
        const int k0 = ks + 2 * j, k1 = k0 + 1;
        float w0, w1;
        if (k0 < NU) w0 = W_rec[k0 * NU + u] * M_rec[k0 * NU + u];
        else         w0 = W_in[(k0 - NU) * NU + u] * M_in[(k0 - NU) * NU + u];
        if (k1 < NU) w1 = W_rec[k1 * NU + u] * M_rec[k1 * NU + u];
        else         w1 = W_in[(k1 - NU) * NU + u] * M_in[(k1 - NU) * NU + u];
        h16x2 t2; t2[0] = (h16)w0; t2[1] = (h16)w1; w[j] = t2;
    }
    const float breg = (tid < NU) ? bias[u] : 0.0f;
    const long xbase = (long)b * SL * NC;
    if (tid < NU) vec[tid] = (h16)0.f;
    else if (tid < NU + NC) vec[tid] = (h16)x[xbase + (tid - NU)];
    __syncthreads();
    const bool xthr = (tid >= NU) && (tid < NU + NC);
    for (int t = 0; t < SL; ++t) {
        float xr = 0.f;
        if (xthr && (t + 1 < SL)) xr = x[xbase + (long)(t + 1) * NC + (tid - NU)];
        const h16x2* v2 = (const h16x2*)(&vec[ks]);
        float acc = 0.f;
#pragma unroll
        for (int j = 0; j < 48; ++j) acc = fdot2f(v2[j], w[j], acc);
        partial[kc][u] = acc;
        __syncthreads();
        if (tid < NU) {
            float s = partial[0][u] + partial[1][u] + partial[2][u] + partial[3][u] + breg;
            float hn = ftanh(s);
            vec[u] = (h16)hn;
            if (u >= NU - NO) out[((long)b * SL + t) * NO + (u - (NU - NO))] = hn;
            if (t == SL - 1)  out[(long)NB * SL * NO + (long)b * NU + u] = hn;
        } else if (xthr && (t + 1 < SL)) vec[tid] = (h16)xr;
        __syncthreads();
    }
}

extern "C" void kernel_launch(void* const* d_in, const int* in_sizes, int n_in,
                              void* d_out, int out_size, void* d_ws, size_t ws_size,
                              hipStream_t stream) {
    (void)in_sizes; (void)n_in; (void)out_size;
    const float* x     = (const float*)d_in[0];
    const float* W_in  = (const float*)d_in[1];
    const float* W_rec = (const float*)d_in[2];
    const float* bias  = (const float*)d_in[3];
    const float* M_in  = (const float*)d_in[4];
    const float* M_rec = (const float*)d_in[5];
    float* out = (float*)d_out;

    const size_t xw_bytes = (size_t)SL * 2 * 256 * 16 * sizeof(h16);   // 134,217,728
    if (ws_size >= xw_bytes) {
        h16* xw = (h16*)d_ws;
        xw_gemm_mfma<<<dim3(SL / 32, 2), dim3(256), 0, stream>>>(x, W_in, bias, M_in, xw);
        rnn_scan_mfma<<<dim3(2), dim3(256), 0, stream>>>(W_rec, M_rec, xw, out);
    } else {
        rnn_scan_fallback<<<dim3(NB), dim3(1024), 0, stream>>>(x, W_in, W_rec, bias, M_in, M_rec, out);
    }
}